// Round 1
// baseline (727.203 us; speedup 1.0000x reference)
//
#include <hip/hip_runtime.h>

// RWKV attention, MI355X. Pipeline:
//   f2bf x4 (weights) -> prep (token-shift mix, fp32->bf16)
//   -> 3x GEMM (xr@Wr^T sigmoid, xk@Wk^T, xv@Wv^T)  [bf16 MFMA, fp32 accum]
//   -> wkv scan (fp32 state, 8192 parallel chains)
//   -> GEMM (attn@Wo^T) -> fp32 out
// Workspace layout (bytes): 5 activation slots of 32MB (bf16 8192x2048) with
// aliasing (v->slot0, attn->slot1), then 4 bf16 weights of 8MB. Total ~201MB.

#define HIDDEN 2048
#define TOUT   2048
#define TT     2048
#define MM     8192   // B*T

typedef __bf16 bf16_t;
typedef __attribute__((ext_vector_type(8))) __bf16 bf16x8;
typedef __attribute__((ext_vector_type(4))) __bf16 bf16x4;
typedef __attribute__((ext_vector_type(4))) float  f32x4;

// ---------------- fp32 -> bf16 weight convert (4M elems, 4/thread) ----------
__global__ __launch_bounds__(256) void f2bf_kernel(const float* __restrict__ src,
                                                   bf16_t* __restrict__ dst) {
  const long i = ((long)blockIdx.x * 256 + threadIdx.x) * 4;
  const float4 v = *reinterpret_cast<const float4*>(src + i);
  bf16x4 o;
  o[0] = (bf16_t)v.x; o[1] = (bf16_t)v.y; o[2] = (bf16_t)v.z; o[3] = (bf16_t)v.w;
  *reinterpret_cast<bf16x4*>(dst + i) = o;
}

// ---------------- token-shift mix: xk/xv/xr = h*mix + h[t-1]*(1-mix) --------
__global__ __launch_bounds__(256) void prep_kernel(const float* __restrict__ h,
    const float* __restrict__ mk, const float* __restrict__ mv,
    const float* __restrict__ mr,
    bf16_t* __restrict__ xk, bf16_t* __restrict__ xv, bf16_t* __restrict__ xr) {
  const long i  = ((long)blockIdx.x * 256 + threadIdx.x) * 4;  // elem index
  const int  c  = (int)(i & (HIDDEN - 1));
  const long bt = i >> 11;
  const int  t  = (int)(bt & (TT - 1));
  const float4 hv = *reinterpret_cast<const float4*>(h + i);
  float4 hp = make_float4(0.f, 0.f, 0.f, 0.f);
  if (t > 0) hp = *reinterpret_cast<const float4*>(h + i - HIDDEN);
  const float4 k4 = *reinterpret_cast<const float4*>(mk + c);
  const float4 v4 = *reinterpret_cast<const float4*>(mv + c);
  const float4 r4 = *reinterpret_cast<const float4*>(mr + c);
  bf16x4 ok, ov, orr;
#define MIX(j, HC, PC)                                         \
  ok[j]  = (bf16_t)(HC * k4.PC + hp.PC * (1.f - k4.PC));       \
  ov[j]  = (bf16_t)(HC * v4.PC + hp.PC * (1.f - v4.PC));       \
  orr[j] = (bf16_t)(HC * r4.PC + hp.PC * (1.f - r4.PC));
  MIX(0, hv.x, x) MIX(1, hv.y, y) MIX(2, hv.z, z) MIX(3, hv.w, w)
#undef MIX
  *reinterpret_cast<bf16x4*>(xk + i) = ok;
  *reinterpret_cast<bf16x4*>(xv + i) = ov;
  *reinterpret_cast<bf16x4*>(xr + i) = orr;
}

// ---------------- GEMM: C[M,N] = A[M,K] * W[N,K]^T  (bf16, fp32 accum) ------
// m97 structure: 128x128 tile, BK=32, 4 waves (2x2) x 64x64 per wave,
// global_load_lds width=16 staging, mfma_f32_16x16x32_bf16.
#define BM 128
#define BN 128
#define BK 32

template<bool SIGMOID, bool OUTF32>
__global__ __launch_bounds__(256) void gemm_bt(const bf16_t* __restrict__ A,
                                               const bf16_t* __restrict__ W,
                                               bf16_t* __restrict__ Cb,
                                               float* __restrict__ Cf) {
  __shared__ bf16_t sA[BM * BK];
  __shared__ bf16_t sB[BN * BK];
  const int tid  = threadIdx.x;
  const int wave = tid >> 6;
  const int lane = tid & 63;
  const int wr   = wave >> 1, wc = wave & 1;
  const long rowA0 = (long)blockIdx.x * BM;
  const long rowB0 = (long)blockIdx.y * BN;

  f32x4 acc[4][4];
#pragma unroll
  for (int m = 0; m < 4; ++m)
#pragma unroll
    for (int n = 0; n < 4; ++n)
#pragma unroll
      for (int q = 0; q < 4; ++q) acc[m][n][q] = 0.f;

  const int kq   = (lane >> 4) * 8;   // K-offset of this lane's fragment
  const int rsel = lane & 15;         // row (A) / col (B) within 16x16

  for (int kt = 0; kt < HIDDEN; kt += BK) {
    __syncthreads();
#pragma unroll
    for (int i = 0; i < 2; ++i) {
      const int e   = i * 2048 + tid * 8;   // elem offset into [128][32] tile
      const int row = e >> 5;
      const int col = e & 31;
      const bf16_t* ga = A + (rowA0 + row) * HIDDEN + kt + col;
      const bf16_t* gw = W + (rowB0 + row) * HIDDEN + kt + col;
      // LDS dest: wave-uniform base; HW adds lane*16.
      __builtin_amdgcn_global_load_lds(
          (const __attribute__((address_space(1))) void*)ga,
          (__attribute__((address_space(3))) void*)(sA + i * 2048 + wave * 512),
          16, 0, 0);
      __builtin_amdgcn_global_load_lds(
          (const __attribute__((address_space(1))) void*)gw,
          (__attribute__((address_space(3))) void*)(sB + i * 2048 + wave * 512),
          16, 0, 0);
    }
    __syncthreads();  // compiler drains vmcnt before s_barrier

    bf16x8 af[4], bw[4];
#pragma unroll
    for (int m = 0; m < 4; ++m)
      af[m] = *reinterpret_cast<const bf16x8*>(sA + (wr * 64 + m * 16 + rsel) * BK + kq);
#pragma unroll
    for (int n = 0; n < 4; ++n)
      bw[n] = *reinterpret_cast<const bf16x8*>(sB + (wc * 64 + n * 16 + rsel) * BK + kq);
#pragma unroll
    for (int m = 0; m < 4; ++m)
#pragma unroll
      for (int n = 0; n < 4; ++n)
        acc[m][n] = __builtin_amdgcn_mfma_f32_16x16x32_bf16(af[m], bw[n], acc[m][n], 0, 0, 0);
  }

  // C/D layout (m89-verified): col = lane&15, row = (lane>>4)*4 + j
  const long crow0 = rowA0 + wr * 64 + (lane >> 4) * 4;
  const long ccol0 = rowB0 + wc * 64 + rsel;
#pragma unroll
  for (int m = 0; m < 4; ++m) {
#pragma unroll
    for (int n = 0; n < 4; ++n) {
#pragma unroll
      for (int j = 0; j < 4; ++j) {
        float val = acc[m][n][j];
        if (SIGMOID) val = 1.f / (1.f + __expf(-val));
        const long row = crow0 + m * 16 + j;
        const long col = ccol0 + n * 16;
        if (OUTF32) Cf[row * TOUT + col] = val;
        else        Cb[row * TOUT + col] = (bf16_t)val;
      }
    }
  }
}

// ---------------- WKV scan: 8192 chains, double-buffered reg batches --------
#define WB 8
__global__ __launch_bounds__(64) void wkv_kernel(const bf16_t* __restrict__ rp,
    const bf16_t* __restrict__ kp, const bf16_t* __restrict__ vp,
    const float* __restrict__ td, const float* __restrict__ tf,
    bf16_t* __restrict__ attn) {
  const int  idx  = blockIdx.x * 64 + threadIdx.x;   // 0..8191 = (b, o)
  const int  o    = idx & (TOUT - 1);
  const long base = (long)(idx >> 11) * TT * TOUT + o;
  const float w = __expf(-__expf(td[o]));
  const float u = tf[o];
  float state = 0.f;
  float r0[WB], k0[WB], v0[WB], r1[WB], k1[WB], v1[WB];
#pragma unroll
  for (int j = 0; j < WB; ++j) {
    const long p = base + (long)j * TOUT;
    r0[j] = (float)rp[p]; k0[j] = (float)kp[p]; v0[j] = (float)vp[p];
  }
  for (int t0 = 0; t0 < TT; t0 += 2 * WB) {
#pragma unroll
    for (int j = 0; j < WB; ++j) {            // prefetch batch1 (t0+WB)
      const long p = base + (long)(t0 + WB + j) * TOUT;
      r1[j] = (float)rp[p]; k1[j] = (float)kp[p]; v1[j] = (float)vp[p];
    }
#pragma unroll
    for (int j = 0; j < WB; ++j) {            // compute batch0
      const float kv = k0[j] * v0[j];
      const float ov = (state + u * kv) * r0[j];
      state = state * w + kv;
      attn[base + (long)(t0 + j) * TOUT] = (bf16_t)ov;
    }
    const int tn = t0 + 2 * WB;
#pragma unroll
    for (int j = 0; j < WB; ++j) {            // prefetch batch0 (t0+2*WB)
      int t = tn + j; if (t > TT - 1) t = TT - 1;   // clamped tail, unused
      const long p = base + (long)t * TOUT;
      r0[j] = (float)rp[p]; k0[j] = (float)kp[p]; v0[j] = (float)vp[p];
    }
#pragma unroll
    for (int j = 0; j < WB; ++j) {            // compute batch1
      const float kv = k1[j] * v1[j];
      const float ov = (state + u * kv) * r1[j];
      state = state * w + kv;
      attn[base + (long)(t0 + WB + j) * TOUT] = (bf16_t)ov;
    }
  }
}

// ---------------- launch -----------------------------------------------------
extern "C" void kernel_launch(void* const* d_in, const int* in_sizes, int n_in,
                              void* d_out, int out_size, void* d_ws, size_t ws_size,
                              hipStream_t stream) {
  const float* h  = (const float*)d_in[0];
  const float* Wr = (const float*)d_in[1];
  const float* Wk = (const float*)d_in[2];
  const float* Wv = (const float*)d_in[3];
  const float* Wo = (const float*)d_in[4];
  const float* td = (const float*)d_in[5];
  const float* tf = (const float*)d_in[6];
  const float* mk = (const float*)d_in[7];
  const float* mv = (const float*)d_in[8];
  const float* mr = (const float*)d_in[9];
  float* out = (float*)d_out;

  char* ws = (char*)d_ws;
  const size_t S2 = (size_t)MM * TOUT * sizeof(bf16_t);   // 32 MiB
  bf16_t* xr   = (bf16_t*)(ws + 0 * S2);
  bf16_t* xk   = (bf16_t*)(ws + 1 * S2);
  bf16_t* xv   = (bf16_t*)(ws + 2 * S2);
  bf16_t* rr   = (bf16_t*)(ws + 3 * S2);
  bf16_t* kk   = (bf16_t*)(ws + 4 * S2);
  bf16_t* vv   = xr;   // alias: xr dead after r-GEMM
  bf16_t* attn = xk;   // alias: xk dead after k-GEMM
  const size_t WSZ = (size_t)TOUT * HIDDEN;               // 4M elems
  bf16_t* Wr2 = (bf16_t*)(ws + 5 * S2);
  bf16_t* Wk2 = Wr2 + WSZ;
  bf16_t* Wv2 = Wk2 + WSZ;
  bf16_t* Wo2 = Wv2 + WSZ;

  f2bf_kernel<<<4096, 256, 0, stream>>>(Wr, Wr2);
  f2bf_kernel<<<4096, 256, 0, stream>>>(Wk, Wk2);
  f2bf_kernel<<<4096, 256, 0, stream>>>(Wv, Wv2);
  f2bf_kernel<<<4096, 256, 0, stream>>>(Wo, Wo2);

  prep_kernel<<<16384, 256, 0, stream>>>(h, mk, mv, mr, xk, xv, xr);

  dim3 gg(MM / BM, TOUT / BN);
  gemm_bt<true , false><<<gg, 256, 0, stream>>>(xr, Wr2, rr, nullptr);
  gemm_bt<false, false><<<gg, 256, 0, stream>>>(xk, Wk2, kk, nullptr);
  gemm_bt<false, false><<<gg, 256, 0, stream>>>(xv, Wv2, vv, nullptr);

  wkv_kernel<<<MM / TOUT * TOUT / 64 * 0 + 128, 64, 0, stream>>>(rr, kk, vv, td, tf, attn);

  gemm_bt<false, true ><<<gg, 256, 0, stream>>>(attn, Wo2, nullptr, out);
}

// Round 2
// 490.510 us; speedup vs baseline: 1.4825x; 1.4825x over previous
//
#include <hip/hip_runtime.h>

// RWKV attention, MI355X.
//   f2bf x4 -> prep (token-shift mix, fp32->bf16)
//   -> 3x GEMM256 (xr@Wr^T sigmoid, xk@Wk^T, xv@Wv^T)  [bf16 MFMA, fp32 accum]
//   -> wkv chunked scan (pass1 chunk states, pass3 outputs w/ fused prefix)
//   -> GEMM256 (attn@Wo^T) -> fp32 out
// GEMM256: 256x256 tile, BK=64, 512 thr (2x4 waves, 128x64/wave), 128KiB LDS
// double-buffered, counted vmcnt(8) + raw s_barrier (2 K-tiles in flight),
// XOR-swizzled LDS (granule ^= row&7) via pre-swizzled global source (linear
// global_load_lds dest), setprio around MFMA bursts.

#define HIDDEN 2048
#define TOUT   2048
#define TT     2048
#define MM     8192

typedef __bf16 bf16_t;
typedef __attribute__((ext_vector_type(8))) __bf16 bf16x8;
typedef __attribute__((ext_vector_type(4))) __bf16 bf16x4;
typedef __attribute__((ext_vector_type(4))) float  f32x4;

// ---------------- fp32 -> bf16 weight convert ------------------------------
__global__ __launch_bounds__(256) void f2bf_kernel(const float* __restrict__ src,
                                                   bf16_t* __restrict__ dst) {
  const long i = ((long)blockIdx.x * 256 + threadIdx.x) * 4;
  const float4 v = *reinterpret_cast<const float4*>(src + i);
  bf16x4 o;
  o[0] = (bf16_t)v.x; o[1] = (bf16_t)v.y; o[2] = (bf16_t)v.z; o[3] = (bf16_t)v.w;
  *reinterpret_cast<bf16x4*>(dst + i) = o;
}

// ---------------- token-shift mix ------------------------------------------
__global__ __launch_bounds__(256) void prep_kernel(const float* __restrict__ h,
    const float* __restrict__ mk, const float* __restrict__ mv,
    const float* __restrict__ mr,
    bf16_t* __restrict__ xk, bf16_t* __restrict__ xv, bf16_t* __restrict__ xr) {
  const long i  = ((long)blockIdx.x * 256 + threadIdx.x) * 4;
  const int  c  = (int)(i & (HIDDEN - 1));
  const long bt = i >> 11;
  const int  t  = (int)(bt & (TT - 1));
  const float4 hv = *reinterpret_cast<const float4*>(h + i);
  float4 hp = make_float4(0.f, 0.f, 0.f, 0.f);
  if (t > 0) hp = *reinterpret_cast<const float4*>(h + i - HIDDEN);
  const float4 k4 = *reinterpret_cast<const float4*>(mk + c);
  const float4 v4 = *reinterpret_cast<const float4*>(mv + c);
  const float4 r4 = *reinterpret_cast<const float4*>(mr + c);
  bf16x4 ok, ov, orr;
#define MIX(j, HC, PC)                                         \
  ok[j]  = (bf16_t)(HC * k4.PC + hp.PC * (1.f - k4.PC));       \
  ov[j]  = (bf16_t)(HC * v4.PC + hp.PC * (1.f - v4.PC));       \
  orr[j] = (bf16_t)(HC * r4.PC + hp.PC * (1.f - r4.PC));
  MIX(0, hv.x, x) MIX(1, hv.y, y) MIX(2, hv.z, z) MIX(3, hv.w, w)
#undef MIX
  *reinterpret_cast<bf16x4*>(xk + i) = ok;
  *reinterpret_cast<bf16x4*>(xv + i) = ov;
  *reinterpret_cast<bf16x4*>(xr + i) = orr;
}

// ---------------- GEMM256: C[M,N] = A[M,K] * W[N,K]^T ----------------------
#define GBM 256
#define GBN 256
#define GBK 64

template<bool SIGMOID, bool OUTF32>
__global__ __launch_bounds__(512, 2) void gemm256(const bf16_t* __restrict__ A,
                                                  const bf16_t* __restrict__ W,
                                                  bf16_t* __restrict__ Cb,
                                                  float* __restrict__ Cf) {
  __shared__ __align__(16) char lds[131072];  // A:[0,64K) B:[64K,128K), dbuf ^0x8000
  const int tid = threadIdx.x, wave = tid >> 6, lane = tid & 63;
  const int wr = wave >> 2, wc = wave & 3;           // 2 (M) x 4 (N)
  const long rowA0 = (long)blockIdx.x * GBM;
  const long rowB0 = (long)blockIdx.y * GBN;
  const bf16_t* aB = A + rowA0 * HIDDEN;
  const bf16_t* wB = W + rowB0 * HIDDEN;

  // staging: instr i covers rows [i*64+wave*8, +8); lane -> row=R0+(l>>3),
  // LDS granule l&7. Pre-swizzle SOURCE: global granule = (l&7)^(row&7).
  const int sgofs = (wave * 8 + (lane >> 3)) * HIDDEN + (((lane & 7) ^ (lane >> 3)) << 3);
  const int ldst  = wave * 1024;                     // wave*8 rows * 128B

#define STAGE(J, BUFX) do {                                                     \
    const int kt_ = (J) * GBK;                                                  \
    _Pragma("unroll")                                                           \
    for (int i_ = 0; i_ < 4; ++i_) {                                            \
      __builtin_amdgcn_global_load_lds(                                         \
        (const __attribute__((address_space(1))) void*)(aB + sgofs + i_ * (64 * HIDDEN) + kt_), \
        (__attribute__((address_space(3))) void*)(lds + (BUFX) + ldst + i_ * 8192), 16, 0, 0);  \
      __builtin_amdgcn_global_load_lds(                                         \
        (const __attribute__((address_space(1))) void*)(wB + sgofs + i_ * (64 * HIDDEN) + kt_), \
        (__attribute__((address_space(3))) void*)(lds + 65536 + (BUFX) + ldst + i_ * 8192), 16, 0, 0); \
    } } while (0)

  // ds_read offsets (buf0-relative, swizzled): byte = row*128 + ((g0^(row&7))<<4)
  const int rsel = lane & 15, g0 = lane >> 4;
  int offA[8], offB[4];
#pragma unroll
  for (int m = 0; m < 8; ++m) {
    const int row = wr * 128 + m * 16 + rsel;
    offA[m] = row * 128 + ((g0 ^ (row & 7)) << 4);
  }
#pragma unroll
  for (int n = 0; n < 4; ++n) {
    const int row = wc * 64 + n * 16 + rsel;
    offB[n] = 65536 + row * 128 + ((g0 ^ (row & 7)) << 4);
  }

  f32x4 acc[8][4];
#pragma unroll
  for (int m = 0; m < 8; ++m)
#pragma unroll
    for (int n = 0; n < 4; ++n)
#pragma unroll
      for (int q = 0; q < 4; ++q) acc[m][n][q] = 0.f;

  STAGE(0, 0);
  STAGE(1, 32768);

  int bufx = 0;
  for (int j = 0; j < 32; ++j) {
    // K-tile j landed (tile j+1's 8 loads may stay in flight)
    if (j < 31) { asm volatile("s_waitcnt vmcnt(8)" ::: "memory"); }
    else        { asm volatile("s_waitcnt vmcnt(0)" ::: "memory"); }
    __builtin_amdgcn_sched_barrier(0);
    __builtin_amdgcn_s_barrier();

    bf16x8 a0[8], b0[4], a1[8], b1[4];
#pragma unroll
    for (int m = 0; m < 8; ++m) a0[m] = *reinterpret_cast<const bf16x8*>(lds + (offA[m] ^ bufx));
#pragma unroll
    for (int n = 0; n < 4; ++n) b0[n] = *reinterpret_cast<const bf16x8*>(lds + (offB[n] ^ bufx));
    __builtin_amdgcn_s_setprio(1);
#pragma unroll
    for (int m = 0; m < 8; ++m)
#pragma unroll
      for (int n = 0; n < 4; ++n)
        acc[m][n] = __builtin_amdgcn_mfma_f32_16x16x32_bf16(a0[m], b0[n], acc[m][n], 0, 0, 0);
    __builtin_amdgcn_s_setprio(0);
    // K-slice 1 lives at granule+4 => byte offset ^ 64 (g0<4 so +4 == ^4)
#pragma unroll
    for (int m = 0; m < 8; ++m) a1[m] = *reinterpret_cast<const bf16x8*>(lds + (offA[m] ^ bufx ^ 64));
#pragma unroll
    for (int n = 0; n < 4; ++n) b1[n] = *reinterpret_cast<const bf16x8*>(lds + (offB[n] ^ bufx ^ 64));
    // drain own ds_reads, then barrier: no wave still reads buf[cur] after this
    asm volatile("s_waitcnt lgkmcnt(0)" ::: "memory");
    __builtin_amdgcn_sched_barrier(0);
    __builtin_amdgcn_s_barrier();
    if (j < 30) STAGE(j + 2, bufx);   // overwrite now-safe buffer
    __builtin_amdgcn_s_setprio(1);
#pragma unroll
    for (int m = 0; m < 8; ++m)
#pragma unroll
      for (int n = 0; n < 4; ++n)
        acc[m][n] = __builtin_amdgcn_mfma_f32_16x16x32_bf16(a1[m], b1[n], acc[m][n], 0, 0, 0);
    __builtin_amdgcn_s_setprio(0);
    bufx ^= 32768;
  }
#undef STAGE

  // C/D layout: col = lane&15, row = (lane>>4)*4 + q
  const long crow0 = rowA0 + wr * 128 + g0 * 4;
  const long ccol0 = rowB0 + wc * 64 + rsel;
#pragma unroll
  for (int m = 0; m < 8; ++m) {
#pragma unroll
    for (int n = 0; n < 4; ++n) {
#pragma unroll
      for (int q = 0; q < 4; ++q) {
        float val = acc[m][n][q];
        if (SIGMOID) val = 1.f / (1.f + __expf(-val));
        const long row = crow0 + m * 16 + q;
        const long col = ccol0 + n * 16;
        if (OUTF32) Cf[row * TOUT + col] = val;
        else        Cb[row * TOUT + col] = (bf16_t)val;
      }
    }
  }
}

// ---------------- WKV chunked scan -----------------------------------------
// Linear recurrence: state_{t+1} = state_t * w + k_t v_t. Split T into NCH
// chunks of CL; pass1 computes per-chunk local final states (zero init);
// pass3 rebuilds chunk-initial state from the chunk-state table (geometric
// prefix, w^CL per hop) and emits outputs. 8 chains/thread (bf16x8 loads).
#define CL  64
#define NCH 32

__global__ __launch_bounds__(256) void wkv_state_kernel(
    const bf16_t* __restrict__ kp, const bf16_t* __restrict__ vp,
    const float* __restrict__ td, float* __restrict__ cs /*[NCH][8192]*/) {
  const int c8 = blockIdx.x * 256 + threadIdx.x;   // 0..1023
  const int ch = blockIdx.y;                       // 0..NCH-1
  const int o0 = (c8 * 8) & (TOUT - 1);
  const int b  = c8 >> 8;
  const long base = ((long)b * TT + ch * CL) * TOUT + o0;
  float w[8], s[8];
#pragma unroll
  for (int i = 0; i < 8; ++i) { w[i] = __expf(-__expf(td[o0 + i])); s[i] = 0.f; }
  for (int t = 0; t < CL; ++t) {
    const bf16x8 k8 = *reinterpret_cast<const bf16x8*>(kp + base + (long)t * TOUT);
    const bf16x8 v8 = *reinterpret_cast<const bf16x8*>(vp + base + (long)t * TOUT);
#pragma unroll
    for (int i = 0; i < 8; ++i) s[i] = s[i] * w[i] + (float)k8[i] * (float)v8[i];
  }
  float4* csv = reinterpret_cast<float4*>(cs + ch * MM + c8 * 8);
  csv[0] = make_float4(s[0], s[1], s[2], s[3]);
  csv[1] = make_float4(s[4], s[5], s[6], s[7]);
}

__global__ __launch_bounds__(256) void wkv_out_kernel(
    const bf16_t* __restrict__ rp, const bf16_t* __restrict__ kp,
    const bf16_t* __restrict__ vp, const float* __restrict__ td,
    const float* __restrict__ tf, const float* __restrict__ cs,
    bf16_t* __restrict__ attn) {
  const int c8 = blockIdx.x * 256 + threadIdx.x;
  const int ch = blockIdx.y;
  const int o0 = (c8 * 8) & (TOUT - 1);
  const int b  = c8 >> 8;
  const long base = ((long)b * TT + ch * CL) * TOUT + o0;
  float w[8], u[8], wc[8], S[8];
#pragma unroll
  for (int i = 0; i < 8; ++i) {
    const float e = __expf(td[o0 + i]);
    w[i]  = __expf(-e);
    wc[i] = __expf(-e * (float)CL);   // w^CL
    u[i]  = tf[o0 + i];
    S[i]  = 0.f;
  }
  for (int j2 = 0; j2 < ch; ++j2) {   // prefix over earlier chunks
    const float4 s0 = *reinterpret_cast<const float4*>(cs + j2 * MM + c8 * 8);
    const float4 s1 = *reinterpret_cast<const float4*>(cs + j2 * MM + c8 * 8 + 4);
    S[0] = S[0] * wc[0] + s0.x; S[1] = S[1] * wc[1] + s0.y;
    S[2] = S[2] * wc[2] + s0.z; S[3] = S[3] * wc[3] + s0.w;
    S[4] = S[4] * wc[4] + s1.x; S[5] = S[5] * wc[5] + s1.y;
    S[6] = S[6] * wc[6] + s1.z; S[7] = S[7] * wc[7] + s1.w;
  }
  for (int t = 0; t < CL; ++t) {
    const bf16x8 r8 = *reinterpret_cast<const bf16x8*>(rp + base + (long)t * TOUT);
    const bf16x8 k8 = *reinterpret_cast<const bf16x8*>(kp + base + (long)t * TOUT);
    const bf16x8 v8 = *reinterpret_cast<const bf16x8*>(vp + base + (long)t * TOUT);
    bf16x8 o8;
#pragma unroll
    for (int i = 0; i < 8; ++i) {
      const float kv = (float)k8[i] * (float)v8[i];
      o8[i] = (bf16_t)((S[i] + u[i] * kv) * (float)r8[i]);
      S[i] = S[i] * w[i] + kv;
    }
    *reinterpret_cast<bf16x8*>(attn + base + (long)t * TOUT) = o8;
  }
}

// ---------------- launch ----------------------------------------------------
extern "C" void kernel_launch(void* const* d_in, const int* in_sizes, int n_in,
                              void* d_out, int out_size, void* d_ws, size_t ws_size,
                              hipStream_t stream) {
  const float* h  = (const float*)d_in[0];
  const float* Wr = (const float*)d_in[1];
  const float* Wk = (const float*)d_in[2];
  const float* Wv = (const float*)d_in[3];
  const float* Wo = (const float*)d_in[4];
  const float* td = (const float*)d_in[5];
  const float* tf = (const float*)d_in[6];
  const float* mk = (const float*)d_in[7];
  const float* mv = (const float*)d_in[8];
  const float* mr = (const float*)d_in[9];
  float* out = (float*)d_out;

  char* ws = (char*)d_ws;
  const size_t S2 = (size_t)MM * TOUT * sizeof(bf16_t);   // 32 MiB
  bf16_t* xr   = (bf16_t*)(ws + 0 * S2);
  bf16_t* xk   = (bf16_t*)(ws + 1 * S2);
  bf16_t* xv   = (bf16_t*)(ws + 2 * S2);
  bf16_t* rr   = (bf16_t*)(ws + 3 * S2);
  bf16_t* kk   = (bf16_t*)(ws + 4 * S2);
  bf16_t* vv   = xr;                     // xr dead after r-GEMM
  bf16_t* attn = xk;                     // xk dead after k-GEMM
  float*  cs   = (float*)xv;             // xv dead after v-GEMM (1 MiB used)
  const size_t WSZ = (size_t)TOUT * HIDDEN;
  bf16_t* Wr2 = (bf16_t*)(ws + 5 * S2);
  bf16_t* Wk2 = Wr2 + WSZ;
  bf16_t* Wv2 = Wk2 + WSZ;
  bf16_t* Wo2 = Wv2 + WSZ;

  f2bf_kernel<<<4096, 256, 0, stream>>>(Wr, Wr2);
  f2bf_kernel<<<4096, 256, 0, stream>>>(Wk, Wk2);
  f2bf_kernel<<<4096, 256, 0, stream>>>(Wv, Wv2);
  f2bf_kernel<<<4096, 256, 0, stream>>>(Wo, Wo2);

  prep_kernel<<<16384, 256, 0, stream>>>(h, mk, mv, mr, xk, xv, xr);

  dim3 gg(MM / GBM, TOUT / GBN);   // 32 x 8
  gemm256<true , false><<<gg, 512, 0, stream>>>(xr, Wr2, rr, nullptr);
  gemm256<false, false><<<gg, 512, 0, stream>>>(xk, Wk2, kk, nullptr);
  gemm256<false, false><<<gg, 512, 0, stream>>>(xv, Wv2, vv, nullptr);

  dim3 wg(4, NCH);
  wkv_state_kernel<<<wg, 256, 0, stream>>>(kk, vv, td, cs);
  wkv_out_kernel<<<wg, 256, 0, stream>>>(rr, kk, vv, td, tf, cs, attn);

  gemm256<false, true ><<<gg, 512, 0, stream>>>(attn, Wo2, nullptr, out);
}

// Round 3
// 487.877 us; speedup vs baseline: 1.4905x; 1.0054x over previous
//
#include <hip/hip_runtime.h>

// RWKV attention, MI355X.
//   f2bf4 (4 weights, fused) -> prep (token-shift mix, fp32->bf16)
//   -> 3x GEMM256 (xr@Wr^T sigmoid, xk@Wk^T, xv@Wv^T)  [bf16 MFMA, fp32 accum]
//   -> wkv chunked scan (pass1 chunk states, pass2 outputs w/ fused prefix)
//   -> GEMM256 (attn@Wo^T) -> fp32 out
// GEMM256: 8-phase schedule (m201 port). 256x256 tile, BK=64, 8 waves (2Mx4N,
// 128x64/wave), 128KiB LDS dbuf, XOR-swizzled (granule ^= row&7) via
// pre-swizzled global source + swizzled ds_read. Per K-tile: 4 phases =
// C-quadrants with 12/8/4/0 ds_reads, 1 half-tile stage each, 2 barriers each,
// setprio around 16-MFMA bursts, counted vmcnt(4) at ph4 (never 0 mid-loop).
// Staging map (derived, read-complete-before-stage verified):
//   ph1: t(j+1) B-h0 (idle buf)   ph2: t(j+1) B-h1 (idle buf)
//   ph3: t(j+2) A-h0 (live buf, A reads done ph2)   ph4: t(j+2) A-h1 + vmcnt(4)

#define HIDDEN 2048
#define TOUT   2048
#define TT     2048
#define MM     8192
#define NT     32     // K / GBK

typedef __bf16 bf16_t;
typedef __attribute__((ext_vector_type(8))) __bf16 bf16x8;
typedef __attribute__((ext_vector_type(4))) float  f32x4;

// ---------------- fp32 -> bf16 weight convert, all 4 weights ----------------
__global__ __launch_bounds__(256) void f2bf4_kernel(
    const float* __restrict__ s0, const float* __restrict__ s1,
    const float* __restrict__ s2, const float* __restrict__ s3,
    bf16_t* __restrict__ d0, bf16_t* __restrict__ d1,
    bf16_t* __restrict__ d2, bf16_t* __restrict__ d3) {
  const float* s; bf16_t* d;
  switch (blockIdx.y) {
    case 0:  s = s0; d = d0; break;
    case 1:  s = s1; d = d1; break;
    case 2:  s = s2; d = d2; break;
    default: s = s3; d = d3; break;
  }
  const long i = ((long)blockIdx.x * 256 + threadIdx.x) * 8;
  const float4 a = *reinterpret_cast<const float4*>(s + i);
  const float4 b = *reinterpret_cast<const float4*>(s + i + 4);
  bf16x8 o;
  o[0] = (bf16_t)a.x; o[1] = (bf16_t)a.y; o[2] = (bf16_t)a.z; o[3] = (bf16_t)a.w;
  o[4] = (bf16_t)b.x; o[5] = (bf16_t)b.y; o[6] = (bf16_t)b.z; o[7] = (bf16_t)b.w;
  *reinterpret_cast<bf16x8*>(d + i) = o;
}

// ---------------- token-shift mix (8 elem/thread) ---------------------------
__global__ __launch_bounds__(256) void prep_kernel(const float* __restrict__ h,
    const float* __restrict__ mk, const float* __restrict__ mv,
    const float* __restrict__ mr,
    bf16_t* __restrict__ xk, bf16_t* __restrict__ xv, bf16_t* __restrict__ xr) {
  const long i = ((long)blockIdx.x * 256 + threadIdx.x) * 8;
  const int  c = (int)(i & (HIDDEN - 1));
  const int  t = (int)((i >> 11) & (TT - 1));
  float hv[8], hp[8], k8[8], v8[8], r8[8];
  *reinterpret_cast<float4*>(hv)     = *reinterpret_cast<const float4*>(h + i);
  *reinterpret_cast<float4*>(hv + 4) = *reinterpret_cast<const float4*>(h + i + 4);
  if (t > 0) {
    *reinterpret_cast<float4*>(hp)     = *reinterpret_cast<const float4*>(h + i - HIDDEN);
    *reinterpret_cast<float4*>(hp + 4) = *reinterpret_cast<const float4*>(h + i - HIDDEN + 4);
  } else {
#pragma unroll
    for (int j = 0; j < 8; ++j) hp[j] = 0.f;
  }
  *reinterpret_cast<float4*>(k8)     = *reinterpret_cast<const float4*>(mk + c);
  *reinterpret_cast<float4*>(k8 + 4) = *reinterpret_cast<const float4*>(mk + c + 4);
  *reinterpret_cast<float4*>(v8)     = *reinterpret_cast<const float4*>(mv + c);
  *reinterpret_cast<float4*>(v8 + 4) = *reinterpret_cast<const float4*>(mv + c + 4);
  *reinterpret_cast<float4*>(r8)     = *reinterpret_cast<const float4*>(mr + c);
  *reinterpret_cast<float4*>(r8 + 4) = *reinterpret_cast<const float4*>(mr + c + 4);
  bf16x8 ok, ov, orr;
#pragma unroll
  for (int j = 0; j < 8; ++j) {
    ok[j]  = (bf16_t)(hv[j] * k8[j] + hp[j] * (1.f - k8[j]));
    ov[j]  = (bf16_t)(hv[j] * v8[j] + hp[j] * (1.f - v8[j]));
    orr[j] = (bf16_t)(hv[j] * r8[j] + hp[j] * (1.f - r8[j]));
  }
  *reinterpret_cast<bf16x8*>(xk + i) = ok;
  *reinterpret_cast<bf16x8*>(xv + i) = ov;
  *reinterpret_cast<bf16x8*>(xr + i) = orr;
}

// ---------------- GEMM256 (8-phase): C[M,N] = A[M,K] * W[N,K]^T -------------
#define GBM 256
#define GBN 256
#define GBK 64

template<bool SIGMOID, bool OUTF32>
__global__ __launch_bounds__(512, 2) void gemm256(const bf16_t* __restrict__ A,
                                                  const bf16_t* __restrict__ W,
                                                  bf16_t* __restrict__ Cb,
                                                  float* __restrict__ Cf) {
  __shared__ __align__(16) char lds[131072];  // A:[0,64K) B:[64K,128K), dbuf ^0x8000
  const int tid = threadIdx.x, wave = tid >> 6, lane = tid & 63;
  const int wr = wave >> 2, wc = wave & 3;           // 2 (M) x 4 (N)
  const long rowA0 = (long)blockIdx.x * GBM;
  const long rowB0 = (long)blockIdx.y * GBN;
  const bf16_t* aB = A + rowA0 * HIDDEN;
  const bf16_t* wB = W + rowB0 * HIDDEN;

  // staging: instr i covers rows [i*64+wave*8, +8); lane -> row += l>>3,
  // LDS granule l&7 (linear dest). Pre-swizzle SOURCE: granule (l&7)^(row&7).
  const int sgofs = (wave * 8 + (lane >> 3)) * HIDDEN + (((lane & 7) ^ (lane >> 3)) << 3);
  const int ldst  = wave * 1024;                     // wave*8 rows * 128B

#define STAGE_H(J, OP, HALF) do {                                               \
    const int j_ = (J);                                                         \
    const bf16_t* s_ = (OP) ? wB : aB;                                          \
    const int lb_ = ((OP) ? 65536 : 0) + ((j_ & 1) << 15) + ldst;               \
    _Pragma("unroll")                                                           \
    for (int i_ = 2 * (HALF); i_ < 2 * (HALF) + 2; ++i_) {                      \
      __builtin_amdgcn_global_load_lds(                                         \
        (const __attribute__((address_space(1))) void*)(s_ + sgofs + i_ * (64 * HIDDEN) + j_ * GBK), \
        (__attribute__((address_space(3))) void*)(lds + lb_ + i_ * 8192), 16, 0, 0); \
    } } while (0)

  // ds_read offsets (buf0, k-slice0): byte = row*128 + ((g0^(row&7))<<4)
  const int rsel = lane & 15, g0 = lane >> 4;
  int offA[8], offB[4];
#pragma unroll
  for (int m = 0; m < 8; ++m) {
    const int row = wr * 128 + m * 16 + rsel;
    offA[m] = row * 128 + ((g0 ^ (row & 7)) << 4);
  }
#pragma unroll
  for (int n = 0; n < 4; ++n) {
    const int row = wc * 64 + n * 16 + rsel;
    offB[n] = 65536 + row * 128 + ((g0 ^ (row & 7)) << 4);
  }

  f32x4 acc[8][4];
#pragma unroll
  for (int m = 0; m < 8; ++m)
#pragma unroll
    for (int n = 0; n < 4; ++n)
#pragma unroll
      for (int q = 0; q < 4; ++q) acc[m][n][q] = 0.f;

#define LD(off) (*reinterpret_cast<const bf16x8*>(lds + (off)))
#define MFMA16(AR, M0, BR, N0) do {                                             \
    __builtin_amdgcn_s_setprio(1);                                              \
    _Pragma("unroll")                                                           \
    for (int m_ = 0; m_ < 4; ++m_)                                              \
      _Pragma("unroll")                                                         \
      for (int n_ = 0; n_ < 2; ++n_)                                            \
        _Pragma("unroll")                                                       \
        for (int s_ = 0; s_ < 2; ++s_)                                          \
          acc[(M0) + m_][(N0) + n_] = __builtin_amdgcn_mfma_f32_16x16x32_bf16(  \
              AR[m_][s_], BR[n_][s_], acc[(M0) + m_][(N0) + n_], 0, 0, 0);      \
    __builtin_amdgcn_s_setprio(0); } while (0)
#define PH_SYNC() do {                                                          \
    __builtin_amdgcn_s_barrier();                                               \
    asm volatile("s_waitcnt lgkmcnt(0)" ::: "memory");                          \
    __builtin_amdgcn_sched_barrier(0); } while (0)

  // prologue: t0 all 4 halves + t1 A-halves (12 loads); t0 landed, 4 in flight
  STAGE_H(0, 0, 0); STAGE_H(0, 0, 1); STAGE_H(0, 1, 0); STAGE_H(0, 1, 1);
  STAGE_H(1, 0, 0); STAGE_H(1, 0, 1);
  asm volatile("s_waitcnt vmcnt(4)" ::: "memory");
  __builtin_amdgcn_s_barrier();

  for (int j = 0; j < NT; ++j) {
    const int bufx = (j & 1) << 15;
    bf16x8 aR0[4][2], aR1[4][2], bR0[2][2], bR1[2][2];
    // ---- ph1: Q(0,0)  reads A0(8)+B0(4); stage t(j+1) B-h0
#pragma unroll
    for (int m = 0; m < 4; ++m) { aR0[m][0] = LD(offA[m] ^ bufx); aR0[m][1] = LD(offA[m] ^ bufx ^ 64); }
#pragma unroll
    for (int n = 0; n < 2; ++n) { bR0[n][0] = LD(offB[n] ^ bufx); bR0[n][1] = LD(offB[n] ^ bufx ^ 64); }
    if (j + 1 < NT) STAGE_H(j + 1, 1, 0);
    asm volatile("s_waitcnt lgkmcnt(8)" ::: "memory");
    PH_SYNC();
    MFMA16(aR0, 0, bR0, 0);
    __builtin_amdgcn_s_barrier();
    // ---- ph2: Q(1,0)  reads A1(8); stage t(j+1) B-h1
#pragma unroll
    for (int m = 0; m < 4; ++m) { aR1[m][0] = LD(offA[4 + m] ^ bufx); aR1[m][1] = LD(offA[4 + m] ^ bufx ^ 64); }
    if (j + 1 < NT) STAGE_H(j + 1, 1, 1);
    PH_SYNC();
    MFMA16(aR1, 4, bR0, 0);
    __builtin_amdgcn_s_barrier();
    // ---- ph3: Q(1,1)  reads B1(4); stage t(j+2) A-h0 (A reads of buf done @ph2)
#pragma unroll
    for (int n = 0; n < 2; ++n) { bR1[n][0] = LD(offB[2 + n] ^ bufx); bR1[n][1] = LD(offB[2 + n] ^ bufx ^ 64); }
    if (j + 2 < NT) STAGE_H(j + 2, 0, 0);
    PH_SYNC();
    MFMA16(aR1, 4, bR1, 2);
    __builtin_amdgcn_s_barrier();
    // ---- ph4: Q(0,1)  no reads; stage t(j+2) A-h1; counted vmcnt
    if (j + 2 < NT) STAGE_H(j + 2, 0, 1);
    if (j <= NT - 3)      { asm volatile("s_waitcnt vmcnt(4)" ::: "memory"); }
    else if (j == NT - 2) { asm volatile("s_waitcnt vmcnt(0)" ::: "memory"); }
    __builtin_amdgcn_sched_barrier(0);
    PH_SYNC();
    MFMA16(aR0, 0, bR1, 2);
    __builtin_amdgcn_s_barrier();
  }
#undef STAGE_H
#undef LD
#undef MFMA16
#undef PH_SYNC

  // C/D layout: col = lane&15, row = (lane>>4)*4 + q
  const long crow0 = rowA0 + wr * 128 + g0 * 4;
  const long ccol0 = rowB0 + wc * 64 + rsel;
#pragma unroll
  for (int m = 0; m < 8; ++m) {
#pragma unroll
    for (int n = 0; n < 4; ++n) {
#pragma unroll
      for (int q = 0; q < 4; ++q) {
        float val = acc[m][n][q];
        if (SIGMOID) val = 1.f / (1.f + __expf(-val));
        const long row = crow0 + m * 16 + q;
        const long col = ccol0 + n * 16;
        if (OUTF32) Cf[row * TOUT + col] = val;
        else        Cb[row * TOUT + col] = (bf16_t)val;
      }
    }
  }
}

// ---------------- WKV chunked scan -----------------------------------------
#define CL  64
#define NCH 32

__global__ __launch_bounds__(256) void wkv_state_kernel(
    const bf16_t* __restrict__ kp, const bf16_t* __restrict__ vp,
    const float* __restrict__ td, float* __restrict__ cs /*[NCH][8192]*/) {
  const int c8 = blockIdx.x * 256 + threadIdx.x;   // 0..1023
  const int ch = blockIdx.y;
  const int o0 = (c8 * 8) & (TOUT - 1);
  const int b  = c8 >> 8;
  const long base = ((long)b * TT + ch * CL) * TOUT + o0;
  float w[8], s[8];
#pragma unroll
  for (int i = 0; i < 8; ++i) { w[i] = __expf(-__expf(td[o0 + i])); s[i] = 0.f; }
  for (int t = 0; t < CL; ++t) {
    const bf16x8 k8 = *reinterpret_cast<const bf16x8*>(kp + base + (long)t * TOUT);
    const bf16x8 v8 = *reinterpret_cast<const bf16x8*>(vp + base + (long)t * TOUT);
#pragma unroll
    for (int i = 0; i < 8; ++i) s[i] = s[i] * w[i] + (float)k8[i] * (float)v8[i];
  }
  float4* csv = reinterpret_cast<float4*>(cs + ch * MM + c8 * 8);
  csv[0] = make_float4(s[0], s[1], s[2], s[3]);
  csv[1] = make_float4(s[4], s[5], s[6], s[7]);
}

__global__ __launch_bounds__(256) void wkv_out_kernel(
    const bf16_t* __restrict__ rp, const bf16_t* __restrict__ kp,
    const bf16_t* __restrict__ vp, const float* __restrict__ td,
    const float* __restrict__ tf, const float* __restrict__ cs,
    bf16_t* __restrict__ attn) {
  const int c8 = blockIdx.x * 256 + threadIdx.x;
  const int ch = blockIdx.y;
  const int o0 = (c8 * 8) & (TOUT - 1);
  const int b  = c8 >> 8;
  const long base = ((long)b * TT + ch * CL) * TOUT + o0;
  float w[8], u[8], wc8[8], S[8];
#pragma unroll
  for (int i = 0; i < 8; ++i) {
    const float e = __expf(td[o0 + i]);
    w[i]   = __expf(-e);
    wc8[i] = __expf(-e * (float)CL);   // w^CL
    u[i]   = tf[o0 + i];
    S[i]   = 0.f;
  }
  for (int j2 = 0; j2 < ch; ++j2) {   // prefix over earlier chunks
    const float4 s0 = *reinterpret_cast<const float4*>(cs + j2 * MM + c8 * 8);
    const float4 s1 = *reinterpret_cast<const float4*>(cs + j2 * MM + c8 * 8 + 4);
    S[0] = S[0] * wc8[0] + s0.x; S[1] = S[1] * wc8[1] + s0.y;
    S[2] = S[2] * wc8[2] + s0.z; S[3] = S[3] * wc8[3] + s0.w;
    S[4] = S[4] * wc8[4] + s1.x; S[5] = S[5] * wc8[5] + s1.y;
    S[6] = S[6] * wc8[6] + s1.z; S[7] = S[7] * wc8[7] + s1.w;
  }
  for (int t = 0; t < CL; ++t) {
    const bf16x8 r8 = *reinterpret_cast<const bf16x8*>(rp + base + (long)t * TOUT);
    const bf16x8 k8 = *reinterpret_cast<const bf16x8*>(kp + base + (long)t * TOUT);
    const bf16x8 v8 = *reinterpret_cast<const bf16x8*>(vp + base + (long)t * TOUT);
    bf16x8 o8;
#pragma unroll
    for (int i = 0; i < 8; ++i) {
      const float kv = (float)k8[i] * (float)v8[i];
      o8[i] = (bf16_t)((S[i] + u[i] * kv) * (float)r8[i]);
      S[i] = S[i] * w[i] + kv;
    }
    *reinterpret_cast<bf16x8*>(attn + base + (long)t * TOUT) = o8;
  }
}

// ---------------- launch ----------------------------------------------------
extern "C" void kernel_launch(void* const* d_in, const int* in_sizes, int n_in,
                              void* d_out, int out_size, void* d_ws, size_t ws_size,
                              hipStream_t stream) {
  const float* h  = (const float*)d_in[0];
  const float* Wr = (const float*)d_in[1];
  const float* Wk = (const float*)d_in[2];
  const float* Wv = (const float*)d_in[3];
  const float* Wo = (const float*)d_in[4];
  const float* td = (const float*)d_in[5];
  const float* tf = (const float*)d_in[6];
  const float* mk = (const float*)d_in[7];
  const float* mv = (const float*)d_in[8];
  const float* mr = (const float*)d_in[9];
  float* out = (float*)d_out;

  char* ws = (char*)d_ws;
  const size_t S2 = (size_t)MM * TOUT * sizeof(bf16_t);   // 32 MiB
  bf16_t* xr   = (bf16_t*)(ws + 0 * S2);
  bf16_t* xk   = (bf16_t*)(ws + 1 * S2);
  bf16_t* xv   = (bf16_t*)(ws + 2 * S2);
  bf16_t* rr   = (bf16_t*)(ws + 3 * S2);
  bf16_t* kk   = (bf16_t*)(ws + 4 * S2);
  bf16_t* vv   = xr;                     // xr dead after r-GEMM
  bf16_t* attn = xk;                     // xk dead after k-GEMM
  float*  cs   = (float*)xv;             // xv dead after v-GEMM (1 MiB used)
  const size_t WSZ = (size_t)TOUT * HIDDEN;
  bf16_t* Wr2 = (bf16_t*)(ws + 5 * S2);
  bf16_t* Wk2 = Wr2 + WSZ;
  bf16_t* Wv2 = Wk2 + WSZ;
  bf16_t* Wo2 = Wv2 + WSZ;

  dim3 fg(2048, 4);
  f2bf4_kernel<<<fg, 256, 0, stream>>>(Wr, Wk, Wv, Wo, Wr2, Wk2, Wv2, Wo2);

  prep_kernel<<<8192, 256, 0, stream>>>(h, mk, mv, mr, xk, xv, xr);

  dim3 gg(MM / GBM, TOUT / GBN);   // 32 x 8
  gemm256<true , false><<<gg, 512, 0, stream>>>(xr, Wr2, rr, nullptr);
  gemm256<false, false><<<gg, 512, 0, stream>>>(xk, Wk2, kk, nullptr);
  gemm256<false, false><<<gg, 512, 0, stream>>>(xv, Wv2, vv, nullptr);

  dim3 wg(4, NCH);
  wkv_state_kernel<<<wg, 256, 0, stream>>>(kk, vv, td, cs);
  wkv_out_kernel<<<wg, 256, 0, stream>>>(rr, kk, vv, td, tf, cs, attn);

  gemm256<false, true ><<<gg, 512, 0, stream>>>(attn, Wo2, nullptr, out);
}